// Round 9
// baseline (187.683 us; speedup 1.0000x reference)
//
#include <hip/hip_runtime.h>
#include <stdint.h>

typedef unsigned short u16;
typedef __attribute__((ext_vector_type(8))) short s16x8;
typedef __attribute__((ext_vector_type(4))) float f32x4;
typedef __attribute__((ext_vector_type(16))) float f32x16;

#define MFMA_BF16(a, b, c) __builtin_amdgcn_mfma_f32_16x16x32_bf16((a), (b), (c), 0, 0, 0)
#define MFMA32(a, b, c) __builtin_amdgcn_mfma_f32_32x32x16_bf16((a), (b), (c), 0, 0, 0)

typedef const __attribute__((address_space(1))) uint32_t* gas1_t;
typedef __attribute__((address_space(3))) uint32_t* las3_t;
#define GLDS16(dst, src) __builtin_amdgcn_global_load_lds((gas1_t)(src), (las3_t)(dst), 16, 0, 0)

static __device__ __forceinline__ u16 f2bf(float f) {
    uint32_t u = __float_as_uint(f);
    u = (u + 0x7fffu + ((u >> 16) & 1u)) >> 16;
    return (u16)u;
}
static __device__ __forceinline__ uint32_t pk2bf(float a, float b) {
    return (uint32_t)f2bf(a) | ((uint32_t)f2bf(b) << 16);
}
static __device__ __forceinline__ float bf2f(u16 h) {
    return __uint_as_float(((uint32_t)h) << 16);
}

// ---------------- prep: x -> bf16  AND  W[k][n] f32 -> Wt[n][k] bf16 (fused) -------
__global__ __launch_bounds__(256) void k_prep(const float* __restrict__ x, u16* __restrict__ xb,
                                              const float* __restrict__ w0, const float* __restrict__ w1,
                                              const float* __restrict__ w2, const float* __restrict__ w3,
                                              u16* __restrict__ t0, u16* __restrict__ t1,
                                              u16* __restrict__ t2, u16* __restrict__ t3) {
    __shared__ float tile[32][33];
    const int bid = blockIdx.x, t = threadIdx.x;
    if (bid < 1536) {
        const int i = (bid * 256 + t) * 8;
        f32x4 a = *(const f32x4*)(x + i);
        f32x4 b = *(const f32x4*)(x + i + 4);
        s16x8 r;
        r[0] = (short)f2bf(a[0]); r[1] = (short)f2bf(a[1]);
        r[2] = (short)f2bf(a[2]); r[3] = (short)f2bf(a[3]);
        r[4] = (short)f2bf(b[0]); r[5] = (short)f2bf(b[1]);
        r[6] = (short)f2bf(b[2]); r[7] = (short)f2bf(b[3]);
        *(s16x8*)(xb + i) = r;
        return;
    }
    const int u = bid - 1536;
    const int z = u / 576, r2 = u - z * 576;
    const float* W; u16* T;
    switch (z) {
        case 0:  W = w0; T = t0; break;
        case 1:  W = w1; T = t1; break;
        case 2:  W = w2; T = t2; break;
        default: W = w3; T = t3; break;
    }
    const int n0 = (r2 % 24) * 32, k0 = (r2 / 24) * 32;
    const int tx = t & 31, ty = t >> 5;
#pragma unroll
    for (int i = 0; i < 4; ++i)
        tile[ty + 8 * i][tx] = W[(size_t)(k0 + ty + 8 * i) * 768 + n0 + tx];
    __syncthreads();
#pragma unroll
    for (int i = 0; i < 4; ++i)
        T[(size_t)(n0 + ty + 8 * i) * 768 + k0 + tx] = f2bf(tile[tx][ty + 8 * i]);
}

// ---------------- fused QKV GEMM: 128x64 tiles, double-buffered K-loop ----------
__global__ __launch_bounds__(256) void k_gemm_qkv(
        const u16* __restrict__ A,
        const u16* __restrict__ btq, const u16* __restrict__ btk, const u16* __restrict__ btv,
        const float* __restrict__ bq, const float* __restrict__ bk, const float* __restrict__ bv,
        u16* __restrict__ outq, u16* __restrict__ outk, u16* __restrict__ outv) {
    __shared__ u16 lA[2][128 * 64];
    __shared__ u16 lB[2][64 * 64];
    const int cid = blockIdx.x;
    const int swz = (cid & 7) * 144 + (cid >> 3);
    const int sx = swz % 36, by = swz / 36;
    const int sel = sx / 12, nb = sx - sel * 12;
    const u16* Bt; const float* bias;
    if (sel == 0)      { Bt = btq; bias = bq; }
    else if (sel == 1) { Bt = btk; bias = bk; }
    else               { Bt = btv; bias = bv; }
    const int t = threadIdx.x, lane = t & 63, w = t >> 6;
    const int wr = w >> 1, wc = w & 1;
    const int c = lane & 15, g = lane >> 4;
    const int m0 = by * 128, n0 = nb * 64;
    f32x4 acc[4][2] = {};
    const int lr = lane >> 3, lg = lane & 7;
    const int swz8 = 8 * (lg ^ lr);
    const u16* gA = A  + (size_t)(m0 + w * 8 + lr) * 768 + swz8;
    const u16* gB = Bt + (size_t)(n0 + w * 8 + lr) * 768 + swz8;
#define STG_QKV(bb, kb)                                                        \
    {                                                                          \
        _Pragma("unroll")                                                      \
        for (int j = 0; j < 4; ++j)                                            \
            GLDS16(&lA[bb][j * 2048 + w * 512], gA + (size_t)j * 32 * 768 + (kb)); \
        _Pragma("unroll")                                                      \
        for (int j = 0; j < 2; ++j)                                            \
            GLDS16(&lB[bb][j * 2048 + w * 512], gB + (size_t)j * 32 * 768 + (kb)); \
    }
    STG_QKV(0, 0);
    for (int ki = 0; ki < 12; ++ki) {
        const int cur = ki & 1;
        if (ki + 1 < 12) {
            STG_QKV(cur ^ 1, (ki + 1) * 64);
            asm volatile("s_waitcnt vmcnt(6)" ::: "memory");
        } else {
            asm volatile("s_waitcnt vmcnt(0)" ::: "memory");
        }
        __builtin_amdgcn_sched_barrier(0);
        __builtin_amdgcn_s_barrier();
#pragma unroll
        for (int kh = 0; kh < 2; ++kh) {
            s16x8 af[4], bfr[2];
            const int gg = kh * 4 + g;
#pragma unroll
            for (int i = 0; i < 4; ++i) {
                const int ra = wr * 64 + i * 16 + c;
                af[i] = *(const s16x8*)&lA[cur][ra * 64 + 8 * (gg ^ (ra & 7))];
            }
#pragma unroll
            for (int j = 0; j < 2; ++j) {
                const int rb = wc * 32 + j * 16 + c;
                bfr[j] = *(const s16x8*)&lB[cur][rb * 64 + 8 * (gg ^ (rb & 7))];
            }
#pragma unroll
            for (int i = 0; i < 4; ++i)
#pragma unroll
                for (int j = 0; j < 2; ++j)
                    acc[i][j] = MFMA_BF16(af[i], bfr[j], acc[i][j]);
        }
        __builtin_amdgcn_s_barrier();
    }
#undef STG_QKV
    const float C2 = 0.18033688011112042f;  // (1/8)*log2(e), folded into Q
    const int h = nb;
    if (sel < 2) {
        u16* outp = (sel == 0) ? outq : outk;
        const float osc = (sel == 0) ? C2 : 1.0f;
#pragma unroll
        for (int i = 0; i < 4; ++i)
#pragma unroll
            for (int j = 0; j < 2; ++j) {
                const int hd = wc * 32 + j * 16 + c;
                const float bvv = bias[n0 + hd];
#pragma unroll
                for (int rr = 0; rr < 4; ++rr) {
                    const int m = m0 + wr * 64 + i * 16 + g * 4 + rr;
                    const int b = m >> 11, s = m & 2047;
                    outp[(((size_t)(b * 12 + h) * 2048 + s) << 6) + hd] =
                        f2bf((acc[i][j][rr] + bvv) * osc);
                }
            }
    } else {
#pragma unroll
        for (int i = 0; i < 4; ++i)
#pragma unroll
            for (int j = 0; j < 2; ++j) {
                const int hd = wc * 32 + j * 16 + c;
                const float bvv = bias[n0 + hd];
                const int m = m0 + wr * 64 + i * 16 + g * 4;
                const int b = m >> 11, s = m & 2047;
                uint64_t pk = (uint64_t)pk2bf(acc[i][j][0] + bvv, acc[i][j][1] + bvv) |
                              ((uint64_t)pk2bf(acc[i][j][2] + bvv, acc[i][j][3] + bvv) << 32);
                *(uint64_t*)&outv[((size_t)(b * 12 + h) * 64 + hd) * 2048 + s] = pk;
            }
    }
}

// ---------------- out-projection GEMM: 64x64, double-buffered ----------------
__global__ __launch_bounds__(256) void k_gemm_out(const u16* __restrict__ A,
                                                  const u16* __restrict__ Bt,
                                                  const float* __restrict__ bias,
                                                  float* __restrict__ out) {
    __shared__ u16 lA[2][64 * 64];
    __shared__ u16 lB[2][64 * 64];
    const int cid = blockIdx.x;
    const int swz = (cid & 7) * 96 + (cid >> 3);
    const int bx = swz % 12, by = swz / 12;
    const int t = threadIdx.x;
    const int lane = t & 63, w = t >> 6;
    const int wr = w >> 1, wc = w & 1;
    const int c = lane & 15, g = lane >> 4;
    const int m0 = by * 64, n0 = bx * 64;
    f32x4 acc[2][2] = {};
    const int lr = lane >> 3, lq = lane & 7;
    const int sq = (lq ^ lr) * 8;
    const u16* gA0 = A  + (size_t)(m0 + w * 16 + lr) * 768 + sq;
    const u16* gA1 = gA0 + 8 * 768;
    const u16* gB0 = Bt + (size_t)(n0 + w * 16 + lr) * 768 + sq;
    const u16* gB1 = gB0 + 8 * 768;
#define STG_OUT(bb, kb)                                                        \
    {                                                                          \
        GLDS16(&lA[bb][w * 1024], gA0 + (kb));                                 \
        GLDS16(&lA[bb][w * 1024 + 512], gA1 + (kb));                           \
        GLDS16(&lB[bb][w * 1024], gB0 + (kb));                                 \
        GLDS16(&lB[bb][w * 1024 + 512], gB1 + (kb));                           \
    }
    STG_OUT(0, 0);
    for (int ki = 0; ki < 12; ++ki) {
        const int cur = ki & 1;
        if (ki + 1 < 12) {
            STG_OUT(cur ^ 1, (ki + 1) * 64);
            asm volatile("s_waitcnt vmcnt(4)" ::: "memory");
        } else {
            asm volatile("s_waitcnt vmcnt(0)" ::: "memory");
        }
        __builtin_amdgcn_sched_barrier(0);
        __builtin_amdgcn_s_barrier();
#pragma unroll
        for (int st = 0; st < 2; ++st) {
            s16x8 af[2], bf[2];
            const int col = st * 32 + g * 8;
#pragma unroll
            for (int i = 0; i < 2; ++i) {
                int ra = wr * 32 + i * 16 + c;
                af[i] = *(const s16x8*)&lA[cur][ra * 64 + (col ^ ((ra & 7) << 3))];
                int rb = wc * 32 + i * 16 + c;
                bf[i] = *(const s16x8*)&lB[cur][rb * 64 + (col ^ ((rb & 7) << 3))];
            }
#pragma unroll
            for (int i = 0; i < 2; ++i)
#pragma unroll
                for (int j = 0; j < 2; ++j)
                    acc[i][j] = MFMA_BF16(af[i], bf[j], acc[i][j]);
        }
        __builtin_amdgcn_s_barrier();
    }
#undef STG_OUT
#pragma unroll
    for (int i = 0; i < 2; ++i)
#pragma unroll
        for (int j = 0; j < 2; ++j) {
            const int n = n0 + wc * 32 + j * 16 + c;
            const float bvv = bias[n];
#pragma unroll
            for (int rr = 0; rr < 4; ++rr) {
                const int m = m0 + wr * 32 + i * 16 + g * 4 + rr;
                out[(size_t)m * 768 + n] = acc[i][j][rr] + bvv;
            }
        }
}

// ---------------- causal flash attention: barrier-free, LDS-free, split-K --------
// Block = 4 independent waves x 32 q-rows (128-row tile), one 512-key segment.
// K read direct from [bh][s][64]; V read direct from V^T [bh][64][s] (both L2-resident).
__device__ static const signed char SLOT_QT[40] = {
    15,15,15,15, 14,14,14,14, 13,13,13,13, 12,12,12,12,
    11,11,11, 10,10,10, 9,9,9, 8,8,8, 7,7, 6,6, 5,5, 4,4, 3, 2, 1, 0};
__device__ static const signed char SLOT_SEG[40] = {
    0,1,2,3, 0,1,2,3, 0,1,2,3, 0,1,2,3,
    0,1,2, 0,1,2, 0,1,2, 0,1,2, 0,1, 0,1, 0,1, 0,1, 0, 0, 0, 0};

__global__ __launch_bounds__(256) void k_attn(const u16* __restrict__ qw,
                                              const u16* __restrict__ kw,
                                              const u16* __restrict__ vt,
                                              u16* __restrict__ ctxb,
                                              u16* __restrict__ pctx,
                                              float* __restrict__ pm,
                                              float* __restrict__ ps) {
    const int bid = blockIdx.x;
    const int slot = bid / 24, j24 = bid - slot * 24;
    const int bh = (j24 & 7) * 3 + (j24 >> 3);
    const int qt = SLOT_QT[slot], seg = SLOT_SEG[slot];
    const int nseg = (2 * (qt + 1) + 7) >> 3;
    const int ch0 = seg * 8;
    const int rem = 2 * (qt + 1) - ch0;
    const int nch = rem < 8 ? rem : 8;
    const int t = threadIdx.x, lane = t & 63, w = t >> 6;   // waves independent
    const int l31 = lane & 31, hi = lane >> 5;
    const int q0w = qt * 128 + w * 32;
    const u16* qp = qw + (size_t)bh * 2048 * 64;
    const u16* kp = kw + (size_t)bh * 2048 * 64;
    const u16* vp = vt + (size_t)bh * 64 * 2048;
    s16x8 qf[4];
#pragma unroll
    for (int dk = 0; dk < 4; ++dk)
        qf[dk] = *(const s16x8*)&qp[(size_t)(q0w + l31) * 64 + dk * 16 + hi * 8];
    const int lastq = q0w + 31;
    // per-wave chunk count: skip fully-masked chunks (no barriers -> free)
    const int lastch = (lastq >> 6) + 1 - ch0;
    const int mynch = nch < lastch ? nch : lastch;
    f32x16 ct[2] = {};               // ctx^T: col=q, rows=hd
    float m2 = -1e30f, ssum = 0.0f;
    for (int ci = 0; ci < mynch; ++ci) {
        const int Kc = (ch0 + ci) * 64;
        // ---- QK^T: K frags direct from global (L2-hit) ----
        const u16* kr0 = kp + (size_t)(Kc + l31) * 64;
        const u16* kr1 = kp + (size_t)(Kc + 32 + l31) * 64;
        f32x16 st[2] = {};
#pragma unroll
        for (int dk = 0; dk < 4; ++dk) {
            const int gr = dk * 2 + hi;
            s16x8 kf0 = *(const s16x8*)&kr0[gr * 8];
            s16x8 kf1 = *(const s16x8*)&kr1[gr * 8];
            st[0] = MFMA32(kf0, qf[dk], st[0]);
            st[1] = MFMA32(kf1, qf[dk], st[1]);
        }
        const int qg = q0w + l31;
        float tv[32];
        if (Kc + 63 <= q0w) {
#pragma unroll
            for (int j = 0; j < 16; ++j) { tv[j] = st[0][j]; tv[16 + j] = st[1][j]; }
        } else {
            const int kb = Kc + 4 * hi;
#pragma unroll
            for (int j = 0; j < 16; ++j) {
                const int kloc = (j & 3) + 8 * (j >> 2);
                tv[j]      = (kb + kloc      <= qg) ? st[0][j] : -1e30f;
                tv[16 + j] = (kb + kloc + 32 <= qg) ? st[1][j] : -1e30f;
            }
        }
        // ---- tree max ----
        float x16[16], x8[8], x4[4];
#pragma unroll
        for (int j = 0; j < 16; ++j) x16[j] = fmaxf(tv[j], tv[j + 16]);
#pragma unroll
        for (int j = 0; j < 8; ++j) x8[j] = fmaxf(x16[j], x16[j + 8]);
#pragma unroll
        for (int j = 0; j < 4; ++j) x4[j] = fmaxf(x8[j], x8[j + 4]);
        const float mt = fmaxf(fmaxf(x4[0], x4[1]), fmaxf(x4[2], x4[3]));
        if (!__all(mt <= m2 + 8.0f)) {
            float mq = fmaxf(mt, __shfl_xor(mt, 32));
            const float mnew = fmaxf(m2, mq);
            const float fac = __builtin_amdgcn_exp2f(m2 - mnew);
            ssum *= fac;
#pragma unroll
            for (int j = 0; j < 16; ++j) { ct[0][j] *= fac; ct[1][j] *= fac; }
            m2 = mnew;
        }
        float p[32];
#pragma unroll
        for (int j = 0; j < 32; ++j) p[j] = __builtin_amdgcn_exp2f(tv[j] - m2);
        // ---- tree sum ----
        float y16[16], y8[8], y4[4];
#pragma unroll
        for (int j = 0; j < 16; ++j) y16[j] = p[j] + p[j + 16];
#pragma unroll
        for (int j = 0; j < 8; ++j) y8[j] = y16[j] + y16[j + 8];
#pragma unroll
        for (int j = 0; j < 4; ++j) y4[j] = y8[j] + y8[j + 4];
        ssum += (y4[0] + y4[1]) + (y4[2] + y4[3]);
        // ---- P -> bf16 B-frags (cvt_pk + permlane32_swap); V direct from global ----
#pragma unroll
        for (int kt = 0; kt < 2; ++kt) {
            uint32_t pcv[8];
#pragma unroll
            for (int x = 0; x < 8; ++x) {
                const int j = kt * 16 + 4 * (x >> 1) + 2 * (x & 1);
                asm volatile("v_cvt_pk_bf16_f32 %0, %1, %2"
                             : "=v"(pcv[x]) : "v"(p[j]), "v"(p[j + 1]));
            }
#pragma unroll
            for (int kl = 0; kl < 2; ++kl) {
                uint32_t a0 = pcv[4 * kl],     b0 = pcv[4 * kl + 2];
                uint32_t a1 = pcv[4 * kl + 1], b1 = pcv[4 * kl + 3];
                asm volatile("v_permlane32_swap_b32 %0, %1" : "+v"(a0), "+v"(b0));
                asm volatile("v_permlane32_swap_b32 %0, %1" : "+v"(a1), "+v"(b1));
                union { uint32_t u[4]; s16x8 v; } pf;
                pf.u[0] = a0; pf.u[1] = a1; pf.u[2] = b0; pf.u[3] = b1;
                const int ko = Kc + (kt * 2 + kl) * 16 + hi * 8;
                s16x8 vf0 = *(const s16x8*)&vp[(size_t)l31 * 2048 + ko];
                s16x8 vf1 = *(const s16x8*)&vp[(size_t)(32 + l31) * 2048 + ko];
                ct[0] = MFMA32(vf0, pf.v, ct[0]);
                ct[1] = MFMA32(vf1, pf.v, ct[1]);
            }
        }
    }
    if (nseg == 1) {
        ssum += __shfl_xor(ssum, 32);
        const float inv = 1.0f / ssum;
        const int b = bh / 12, h = bh - b * 12;
        const size_t base = (size_t)(b * 2048 + q0w + l31) * 768 + h * 64;
#pragma unroll
        for (int ht = 0; ht < 2; ++ht)
#pragma unroll
            for (int a = 0; a < 4; ++a) {
                const int hd = ht * 32 + 8 * a + 4 * hi;
                uint64_t pk = (uint64_t)pk2bf(ct[ht][4 * a] * inv, ct[ht][4 * a + 1] * inv) |
                              ((uint64_t)pk2bf(ct[ht][4 * a + 2] * inv, ct[ht][4 * a + 3] * inv) << 32);
                *(uint64_t*)&ctxb[base + hd] = pk;
            }
    } else {
        const float srow = ssum + __shfl_xor(ssum, 32);
        const int ti = (bh * 16 + qt) * 4 + seg;
        const int row = w * 32 + l31;
        u16* pp = &pctx[(size_t)ti * 8192 + row * 64];
#pragma unroll
        for (int ht = 0; ht < 2; ++ht)
#pragma unroll
            for (int a = 0; a < 4; ++a) {
                const int hd = ht * 32 + 8 * a + 4 * hi;
                uint64_t pk = (uint64_t)pk2bf(ct[ht][4 * a], ct[ht][4 * a + 1]) |
                              ((uint64_t)pk2bf(ct[ht][4 * a + 2], ct[ht][4 * a + 3]) << 32);
                *(uint64_t*)&pp[hd] = pk;
            }
        if (hi == 0) {
            pm[ti * 128 + row] = m2;
            ps[ti * 128 + row] = srow;
        }
    }
}

// ---------------- split-K combine: merge <=4 segments per 128-row tile ----------------
__global__ __launch_bounds__(256) void k_attn_combine(const u16* __restrict__ pctx,
                                                      const float* __restrict__ pm,
                                                      const float* __restrict__ ps,
                                                      u16* __restrict__ ctxb) {
    const int bh = blockIdx.x, qt = blockIdx.y + 4;
    const int nseg = (2 * (qt + 1) + 7) >> 3;
    const int tb = (bh * 16 + qt) * 4;
    const int b = bh / 12, h = bh - b * 12;
#pragma unroll
    for (int it = 0; it < 2; ++it) {
        const int u = threadIdx.x + it * 256;
        const int row = u >> 2, h0 = (u & 3) * 16;
        float mv[4], sv[4];
#pragma unroll
        for (int s = 0; s < 4; ++s) {
            mv[s] = (s < nseg) ? pm[(tb + s) * 128 + row] : -1e30f;
            sv[s] = (s < nseg) ? ps[(tb + s) * 128 + row] : 0.0f;
        }
        const float mstar = fmaxf(fmaxf(mv[0], mv[1]), fmaxf(mv[2], mv[3]));
        float wv[4], S = 0.0f;
#pragma unroll
        for (int s = 0; s < 4; ++s) {
            wv[s] = __builtin_amdgcn_exp2f(mv[s] - mstar);
            S += wv[s] * sv[s];
        }
        float acc[16] = {};
#pragma unroll
        for (int s = 0; s < 4; ++s) {
            if (s < nseg) {
                const u16* pp = &pctx[(size_t)(tb + s) * 8192 + row * 64 + h0];
                const float wgt = wv[s];
#pragma unroll
                for (int e = 0; e < 2; ++e) {
                    s16x8 v = *(const s16x8*)(pp + e * 8);
#pragma unroll
                    for (int x = 0; x < 8; ++x)
                        acc[e * 8 + x] += wgt * bf2f((u16)v[x]);
                }
            }
        }
        const float inv = 1.0f / S;
        u16* op = &ctxb[(size_t)(b * 2048 + qt * 128 + row) * 768 + h * 64 + h0];
        s16x8 o0, o1;
#pragma unroll
        for (int x = 0; x < 8; ++x) {
            o0[x] = (short)f2bf(acc[x] * inv);
            o1[x] = (short)f2bf(acc[8 + x] * inv);
        }
        *(s16x8*)op = o0;
        *(s16x8*)(op + 8) = o1;
    }
}

// ---------------- launch ----------------
extern "C" void kernel_launch(void* const* d_in, const int* in_sizes, int n_in,
                              void* d_out, int out_size, void* d_ws, size_t ws_size,
                              hipStream_t stream) {
    (void)in_sizes; (void)n_in; (void)out_size; (void)ws_size;
    const float* x  = (const float*)d_in[0];
    const float* Wq = (const float*)d_in[1];
    const float* bq = (const float*)d_in[2];
    const float* Wk = (const float*)d_in[3];
    const float* bk = (const float*)d_in[4];
    const float* Wv = (const float*)d_in[5];
    const float* bv = (const float*)d_in[6];
    const float* Wo = (const float*)d_in[7];
    const float* bo = (const float*)d_in[8];
    char* ws = (char*)d_ws;
    u16* xb   = (u16*)(ws);               // 4096*768 bf16      = 6291456 B
    u16* wqt  = (u16*)(ws + 6291456);     // 768*768 bf16 (W^T) = 1179648 B
    u16* wkt  = (u16*)(ws + 7471104);
    u16* wvt  = (u16*)(ws + 8650752);
    u16* wot  = (u16*)(ws + 9830400);
    u16* qwv  = (u16*)(ws + 11010048);    // [24][2048][64] bf16 (Q pre-scaled by C2)
    u16* kwv  = (u16*)(ws + 17301504);
    u16* vtw  = (u16*)(ws + 23592960);    // V^T [24][64][2048] bf16
    u16* ctx  = (u16*)(ws + 29884416);    // [4096][768] bf16, ends 36175872
    u16* pctx = (u16*)(ws + 36175872);    // [24][16][4][128][64] bf16 = 25165824 B
    float* pm = (float*)(ws + 61341696);  // [24][16][4][128] f32 = 786432 B
    float* psu= (float*)(ws + 62128128);  // [24][16][4][128] f32 = 786432 B
    float* out = (float*)d_out;

    k_prep<<<3840, 256, 0, stream>>>(x, xb, Wq, Wk, Wv, Wo, wqt, wkt, wvt, wot);
    k_gemm_qkv<<<1152, 256, 0, stream>>>(xb, wqt, wkt, wvt, bq, bk, bv, qwv, kwv, vtw);
    k_attn<<<960, 256, 0, stream>>>(qwv, kwv, vtw, ctx, pctx, pm, psu);
    k_attn_combine<<<dim3(24, 12), 256, 0, stream>>>(pctx, pm, psu, ctx);
    k_gemm_out<<<768, 256, 0, stream>>>(ctx, wot, bo, out);
}

// Round 10
// 172.030 us; speedup vs baseline: 1.0910x; 1.0910x over previous
//
#include <hip/hip_runtime.h>
#include <stdint.h>

typedef unsigned short u16;
typedef __attribute__((ext_vector_type(8))) short s16x8;
typedef __attribute__((ext_vector_type(4))) float f32x4;
typedef __attribute__((ext_vector_type(16))) float f32x16;

#define MFMA_BF16(a, b, c) __builtin_amdgcn_mfma_f32_16x16x32_bf16((a), (b), (c), 0, 0, 0)
#define MFMA32(a, b, c) __builtin_amdgcn_mfma_f32_32x32x16_bf16((a), (b), (c), 0, 0, 0)

typedef const __attribute__((address_space(1))) uint32_t* gas1_t;
typedef __attribute__((address_space(3))) uint32_t* las3_t;
#define GLDS16(dst, src) __builtin_amdgcn_global_load_lds((gas1_t)(src), (las3_t)(dst), 16, 0, 0)

static __device__ __forceinline__ u16 f2bf(float f) {
    uint32_t u = __float_as_uint(f);
    u = (u + 0x7fffu + ((u >> 16) & 1u)) >> 16;
    return (u16)u;
}
static __device__ __forceinline__ uint32_t pk2bf(float a, float b) {
    return (uint32_t)f2bf(a) | ((uint32_t)f2bf(b) << 16);
}
static __device__ __forceinline__ float bf2f(u16 h) {
    return __uint_as_float(((uint32_t)h) << 16);
}

// ---------------- prep: x -> bf16  AND  W[k][n] f32 -> Wt[n][k] bf16 (fused) -------
__global__ __launch_bounds__(256) void k_prep(const float* __restrict__ x, u16* __restrict__ xb,
                                              const float* __restrict__ w0, const float* __restrict__ w1,
                                              const float* __restrict__ w2, const float* __restrict__ w3,
                                              u16* __restrict__ t0, u16* __restrict__ t1,
                                              u16* __restrict__ t2, u16* __restrict__ t3) {
    __shared__ float tile[32][33];
    const int bid = blockIdx.x, t = threadIdx.x;
    if (bid < 1536) {
        const int i = (bid * 256 + t) * 8;
        f32x4 a = *(const f32x4*)(x + i);
        f32x4 b = *(const f32x4*)(x + i + 4);
        s16x8 r;
        r[0] = (short)f2bf(a[0]); r[1] = (short)f2bf(a[1]);
        r[2] = (short)f2bf(a[2]); r[3] = (short)f2bf(a[3]);
        r[4] = (short)f2bf(b[0]); r[5] = (short)f2bf(b[1]);
        r[6] = (short)f2bf(b[2]); r[7] = (short)f2bf(b[3]);
        *(s16x8*)(xb + i) = r;
        return;
    }
    const int u = bid - 1536;
    const int z = u / 576, r2 = u - z * 576;
    const float* W; u16* T;
    switch (z) {
        case 0:  W = w0; T = t0; break;
        case 1:  W = w1; T = t1; break;
        case 2:  W = w2; T = t2; break;
        default: W = w3; T = t3; break;
    }
    const int n0 = (r2 % 24) * 32, k0 = (r2 / 24) * 32;
    const int tx = t & 31, ty = t >> 5;
#pragma unroll
    for (int i = 0; i < 4; ++i)
        tile[ty + 8 * i][tx] = W[(size_t)(k0 + ty + 8 * i) * 768 + n0 + tx];
    __syncthreads();
#pragma unroll
    for (int i = 0; i < 4; ++i)
        T[(size_t)(n0 + ty + 8 * i) * 768 + k0 + tx] = f2bf(tile[tx][ty + 8 * i]);
}

// ---------------- fused QKV GEMM: 128x64 tiles, double-buffered K-loop ----------
__global__ __launch_bounds__(256) void k_gemm_qkv(
        const u16* __restrict__ A,
        const u16* __restrict__ btq, const u16* __restrict__ btk, const u16* __restrict__ btv,
        const float* __restrict__ bq, const float* __restrict__ bk, const float* __restrict__ bv,
        u16* __restrict__ outq, u16* __restrict__ outk, u16* __restrict__ outv) {
    __shared__ u16 lA[2][128 * 64];
    __shared__ u16 lB[2][64 * 64];
    const int cid = blockIdx.x;
    const int swz = (cid & 7) * 144 + (cid >> 3);
    const int sx = swz % 36, by = swz / 36;
    const int sel = sx / 12, nb = sx - sel * 12;
    const u16* Bt; const float* bias;
    if (sel == 0)      { Bt = btq; bias = bq; }
    else if (sel == 1) { Bt = btk; bias = bk; }
    else               { Bt = btv; bias = bv; }
    const int t = threadIdx.x, lane = t & 63, w = t >> 6;
    const int wr = w >> 1, wc = w & 1;
    const int c = lane & 15, g = lane >> 4;
    const int m0 = by * 128, n0 = nb * 64;
    f32x4 acc[4][2] = {};
    const int lr = lane >> 3, lg = lane & 7;
    const int swz8 = 8 * (lg ^ lr);
    const u16* gA = A  + (size_t)(m0 + w * 8 + lr) * 768 + swz8;
    const u16* gB = Bt + (size_t)(n0 + w * 8 + lr) * 768 + swz8;
#define STG_QKV(bb, kb)                                                        \
    {                                                                          \
        _Pragma("unroll")                                                      \
        for (int j = 0; j < 4; ++j)                                            \
            GLDS16(&lA[bb][j * 2048 + w * 512], gA + (size_t)j * 32 * 768 + (kb)); \
        _Pragma("unroll")                                                      \
        for (int j = 0; j < 2; ++j)                                            \
            GLDS16(&lB[bb][j * 2048 + w * 512], gB + (size_t)j * 32 * 768 + (kb)); \
    }
    STG_QKV(0, 0);
    for (int ki = 0; ki < 12; ++ki) {
        const int cur = ki & 1;
        if (ki + 1 < 12) {
            STG_QKV(cur ^ 1, (ki + 1) * 64);
            asm volatile("s_waitcnt vmcnt(6)" ::: "memory");
        } else {
            asm volatile("s_waitcnt vmcnt(0)" ::: "memory");
        }
        __builtin_amdgcn_sched_barrier(0);
        __builtin_amdgcn_s_barrier();
#pragma unroll
        for (int kh = 0; kh < 2; ++kh) {
            s16x8 af[4], bfr[2];
            const int gg = kh * 4 + g;
#pragma unroll
            for (int i = 0; i < 4; ++i) {
                const int ra = wr * 64 + i * 16 + c;
                af[i] = *(const s16x8*)&lA[cur][ra * 64 + 8 * (gg ^ (ra & 7))];
            }
#pragma unroll
            for (int j = 0; j < 2; ++j) {
                const int rb = wc * 32 + j * 16 + c;
                bfr[j] = *(const s16x8*)&lB[cur][rb * 64 + 8 * (gg ^ (rb & 7))];
            }
#pragma unroll
            for (int i = 0; i < 4; ++i)
#pragma unroll
                for (int j = 0; j < 2; ++j)
                    acc[i][j] = MFMA_BF16(af[i], bfr[j], acc[i][j]);
        }
        __builtin_amdgcn_s_barrier();
    }
#undef STG_QKV
    const float C2 = 0.18033688011112042f;  // (1/8)*log2(e), folded into Q
    const int h = nb;
    if (sel < 2) {
        u16* outp = (sel == 0) ? outq : outk;
        const float osc = (sel == 0) ? C2 : 1.0f;
#pragma unroll
        for (int i = 0; i < 4; ++i)
#pragma unroll
            for (int j = 0; j < 2; ++j) {
                const int hd = wc * 32 + j * 16 + c;
                const float bvv = bias[n0 + hd];
#pragma unroll
                for (int rr = 0; rr < 4; ++rr) {
                    const int m = m0 + wr * 64 + i * 16 + g * 4 + rr;
                    const int b = m >> 11, s = m & 2047;
                    outp[(((size_t)(b * 12 + h) * 2048 + s) << 6) + hd] =
                        f2bf((acc[i][j][rr] + bvv) * osc);
                }
            }
    } else {
#pragma unroll
        for (int i = 0; i < 4; ++i)
#pragma unroll
            for (int j = 0; j < 2; ++j) {
                const int hd = wc * 32 + j * 16 + c;
                const float bvv = bias[n0 + hd];
                const int m = m0 + wr * 64 + i * 16 + g * 4;
                const int b = m >> 11, s = m & 2047;
                uint64_t pk = (uint64_t)pk2bf(acc[i][j][0] + bvv, acc[i][j][1] + bvv) |
                              ((uint64_t)pk2bf(acc[i][j][2] + bvv, acc[i][j][3] + bvv) << 32);
                *(uint64_t*)&outv[((size_t)(b * 12 + h) * 64 + hd) * 2048 + s] = pk;
            }
    }
}

// ---------------- out-projection GEMM: 64x64, double-buffered ----------------
__global__ __launch_bounds__(256) void k_gemm_out(const u16* __restrict__ A,
                                                  const u16* __restrict__ Bt,
                                                  const float* __restrict__ bias,
                                                  float* __restrict__ out) {
    __shared__ u16 lA[2][64 * 64];
    __shared__ u16 lB[2][64 * 64];
    const int cid = blockIdx.x;
    const int swz = (cid & 7) * 96 + (cid >> 3);
    const int bx = swz % 12, by = swz / 12;
    const int t = threadIdx.x;
    const int lane = t & 63, w = t >> 6;
    const int wr = w >> 1, wc = w & 1;
    const int c = lane & 15, g = lane >> 4;
    const int m0 = by * 64, n0 = bx * 64;
    f32x4 acc[2][2] = {};
    const int lr = lane >> 3, lq = lane & 7;
    const int sq = (lq ^ lr) * 8;
    const u16* gA0 = A  + (size_t)(m0 + w * 16 + lr) * 768 + sq;
    const u16* gA1 = gA0 + 8 * 768;
    const u16* gB0 = Bt + (size_t)(n0 + w * 16 + lr) * 768 + sq;
    const u16* gB1 = gB0 + 8 * 768;
#define STG_OUT(bb, kb)                                                        \
    {                                                                          \
        GLDS16(&lA[bb][w * 1024], gA0 + (kb));                                 \
        GLDS16(&lA[bb][w * 1024 + 512], gA1 + (kb));                           \
        GLDS16(&lB[bb][w * 1024], gB0 + (kb));                                 \
        GLDS16(&lB[bb][w * 1024 + 512], gB1 + (kb));                           \
    }
    STG_OUT(0, 0);
    for (int ki = 0; ki < 12; ++ki) {
        const int cur = ki & 1;
        if (ki + 1 < 12) {
            STG_OUT(cur ^ 1, (ki + 1) * 64);
            asm volatile("s_waitcnt vmcnt(4)" ::: "memory");
        } else {
            asm volatile("s_waitcnt vmcnt(0)" ::: "memory");
        }
        __builtin_amdgcn_sched_barrier(0);
        __builtin_amdgcn_s_barrier();
#pragma unroll
        for (int st = 0; st < 2; ++st) {
            s16x8 af[2], bf[2];
            const int col = st * 32 + g * 8;
#pragma unroll
            for (int i = 0; i < 2; ++i) {
                int ra = wr * 32 + i * 16 + c;
                af[i] = *(const s16x8*)&lA[cur][ra * 64 + (col ^ ((ra & 7) << 3))];
                int rb = wc * 32 + i * 16 + c;
                bf[i] = *(const s16x8*)&lB[cur][rb * 64 + (col ^ ((rb & 7) << 3))];
            }
#pragma unroll
            for (int i = 0; i < 2; ++i)
#pragma unroll
                for (int j = 0; j < 2; ++j)
                    acc[i][j] = MFMA_BF16(af[i], bf[j], acc[i][j]);
        }
        __builtin_amdgcn_s_barrier();
    }
#undef STG_OUT
#pragma unroll
    for (int i = 0; i < 2; ++i)
#pragma unroll
        for (int j = 0; j < 2; ++j) {
            const int n = n0 + wc * 32 + j * 16 + c;
            const float bvv = bias[n];
#pragma unroll
            for (int rr = 0; rr < 4; ++rr) {
                const int m = m0 + wr * 32 + i * 16 + g * 4 + rr;
                out[(size_t)m * 768 + n] = acc[i][j][rr] + bvv;
            }
        }
}

// ---------------- causal flash attention: wave-private K staging, no barriers ------
// Block = 4 fully-independent waves x 32 q-rows (128-row tile), one 512-key segment.
// Each wave double-buffers its own 32-key K chunk in private LDS (4 GLDS16/chunk,
// wave-local vmcnt sync only). V read direct from V^T, issued before the fence (T14).
__device__ static const signed char SLOT_QT[40] = {
    15,15,15,15, 14,14,14,14, 13,13,13,13, 12,12,12,12,
    11,11,11, 10,10,10, 9,9,9, 8,8,8, 7,7, 6,6, 5,5, 4,4, 3, 2, 1, 0};
__device__ static const signed char SLOT_SEG[40] = {
    0,1,2,3, 0,1,2,3, 0,1,2,3, 0,1,2,3,
    0,1,2, 0,1,2, 0,1,2, 0,1,2, 0,1, 0,1, 0,1, 0,1, 0, 0, 0, 0};

__global__ __launch_bounds__(256) void k_attn(const u16* __restrict__ qw,
                                              const u16* __restrict__ kw,
                                              const u16* __restrict__ vt,
                                              u16* __restrict__ ctxb,
                                              u16* __restrict__ pctx,
                                              float* __restrict__ pm,
                                              float* __restrict__ ps) {
    __shared__ u16 lK[4][2][32 * 64];   // per-wave private, double-buffered K chunks
    const int bid = blockIdx.x;
    const int slot = bid / 24, j24 = bid - slot * 24;
    const int bh = (j24 & 7) * 3 + (j24 >> 3);   // XCD j24&7 sees heads 3x..3x+2
    const int qt = SLOT_QT[slot], seg = SLOT_SEG[slot];
    const int nseg = (2 * (qt + 1) + 7) >> 3;
    const int ch0 = seg * 16;                    // 32-key chunk index base
    const int t = threadIdx.x, lane = t & 63, w = t >> 6;
    const int l31 = lane & 31, hi = lane >> 5;
    const int q0w = qt * 128 + w * 32;
    const u16* qp = qw + (size_t)bh * 2048 * 64;
    const u16* kp = kw + (size_t)bh * 2048 * 64;
    const u16* vp = vt + (size_t)bh * 64 * 2048;
    s16x8 qf[4];
#pragma unroll
    for (int dk = 0; dk < 4; ++dk)
        qf[dk] = *(const s16x8*)&qp[(size_t)(q0w + l31) * 64 + dk * 16 + hi * 8];
    const int lastq = q0w + 31;
    const int avail = (lastq >> 5) + 1 - ch0;    // per-wave causal chunk count
    const int mynch = avail < 16 ? avail : 16;
    // staging source (pre-swizzled): LDS(r,q) = global(r, q ^ (r&7))
    const int lr = lane >> 3, lg = lane & 7;
    const u16* kpb = kp + (size_t)lr * 64 + 8 * (lg ^ (lr & 7));
    u16* lKw = &lK[w][0][0];
    // loop-invariant K read offsets (u16 units)
    int koff[4];
#pragma unroll
    for (int dk = 0; dk < 4; ++dk)
        koff[dk] = l31 * 64 + 8 * ((dk * 2 + hi) ^ (l31 & 7));
    f32x16 ct[2] = {};               // ctx^T: col=q, rows=hd
    float m2 = -1e30f, ssum = 0.0f;
#define STAGE32(bf, ch)                                                        \
    {                                                                          \
        const u16* ks_ = kpb + (size_t)(ch) * 2048;                            \
        GLDS16(lKw + (bf) * 2048, ks_);                                        \
        GLDS16(lKw + (bf) * 2048 + 512, ks_ + 512);                            \
        GLDS16(lKw + (bf) * 2048 + 1024, ks_ + 1024);                          \
        GLDS16(lKw + (bf) * 2048 + 1536, ks_ + 1536);                          \
    }
    STAGE32(0, ch0);
    for (int ci = 0; ci < mynch; ++ci) {
        const int bf = ci & 1, Kc = (ch0 + ci) * 32;
        // V loads for current chunk (direct, early issue — land under QK+softmax)
        s16x8 vf0[2], vf1[2];
#pragma unroll
        for (int kl = 0; kl < 2; ++kl) {
            const int ko = Kc + kl * 16 + hi * 8;
            vf0[kl] = *(const s16x8*)&vp[(size_t)l31 * 2048 + ko];
            vf1[kl] = *(const s16x8*)&vp[(size_t)(32 + l31) * 2048 + ko];
        }
        if (ci + 1 < mynch) {
            STAGE32(bf ^ 1, ch0 + ci + 1);
            // 8 newer vm ops (4 next-stage + 4 V) -> current stage landed
            asm volatile("s_waitcnt vmcnt(8)" ::: "memory");
        } else {
            asm volatile("s_waitcnt vmcnt(4)" ::: "memory");
        }
        // ---- QK^T: 32 keys x 32 q ----
        f32x16 st = {};
#pragma unroll
        for (int dk = 0; dk < 4; ++dk) {
            s16x8 kf = *(const s16x8*)&lKw[bf * 2048 + koff[dk]];
            st = MFMA32(kf, qf[dk], st);
        }
        // ---- mask (diagonal chunk only) ----
        const int qg = q0w + l31;
        float tv[16];
        if (Kc + 31 <= q0w) {
#pragma unroll
            for (int j = 0; j < 16; ++j) tv[j] = st[j];
        } else {
            const int kb = Kc + 4 * hi;
#pragma unroll
            for (int j = 0; j < 16; ++j) {
                const int kloc = (j & 3) + 8 * (j >> 2);
                tv[j] = (kb + kloc <= qg) ? st[j] : -1e30f;
            }
        }
        // ---- tree max (depth 4) ----
        float x8[8], x4[4];
#pragma unroll
        for (int j = 0; j < 8; ++j) x8[j] = fmaxf(tv[j], tv[j + 8]);
#pragma unroll
        for (int j = 0; j < 4; ++j) x4[j] = fmaxf(x8[j], x8[j + 4]);
        const float mt = fmaxf(fmaxf(x4[0], x4[1]), fmaxf(x4[2], x4[3]));
        if (!__all(mt <= m2 + 8.0f)) {
            float mq = fmaxf(mt, __shfl_xor(mt, 32));
            const float mnew = fmaxf(m2, mq);
            const float fac = __builtin_amdgcn_exp2f(m2 - mnew);
            ssum *= fac;
#pragma unroll
            for (int j = 0; j < 16; ++j) { ct[0][j] *= fac; ct[1][j] *= fac; }
            m2 = mnew;
        }
        float p[16];
#pragma unroll
        for (int j = 0; j < 16; ++j) p[j] = __builtin_amdgcn_exp2f(tv[j] - m2);
        // ---- tree sum ----
        float y8[8], y4[4];
#pragma unroll
        for (int j = 0; j < 8; ++j) y8[j] = p[j] + p[j + 8];
#pragma unroll
        for (int j = 0; j < 4; ++j) y4[j] = y8[j] + y8[j + 4];
        ssum += (y4[0] + y4[1]) + (y4[2] + y4[3]);
        // ---- P -> bf16 B-frags (cvt_pk + permlane32_swap); PV ----
        uint32_t pcv[8];
#pragma unroll
        for (int x = 0; x < 8; ++x) {
            const int j = 4 * (x >> 1) + 2 * (x & 1);
            asm volatile("v_cvt_pk_bf16_f32 %0, %1, %2"
                         : "=v"(pcv[x]) : "v"(p[j]), "v"(p[j + 1]));
        }
#pragma unroll
        for (int kl = 0; kl < 2; ++kl) {
            uint32_t a0 = pcv[4 * kl],     b0 = pcv[4 * kl + 2];
            uint32_t a1 = pcv[4 * kl + 1], b1 = pcv[4 * kl + 3];
            asm volatile("v_permlane32_swap_b32 %0, %1" : "+v"(a0), "+v"(b0));
            asm volatile("v_permlane32_swap_b32 %0, %1" : "+v"(a1), "+v"(b1));
            union { uint32_t u[4]; s16x8 v; } pf;
            pf.u[0] = a0; pf.u[1] = a1; pf.u[2] = b0; pf.u[3] = b1;
            ct[0] = MFMA32(vf0[kl], pf.v, ct[0]);
            ct[1] = MFMA32(vf1[kl], pf.v, ct[1]);
        }
    }
    if (nseg == 1) {
        ssum += __shfl_xor(ssum, 32);
        const float inv = 1.0f / ssum;
        const int b = bh / 12, h = bh - b * 12;
        const size_t base = (size_t)(b * 2048 + q0w + l31) * 768 + h * 64;
#pragma unroll
        for (int ht = 0; ht < 2; ++ht)
#pragma unroll
            for (int a = 0; a < 4; ++a) {
                const int hd = ht * 32 + 8 * a + 4 * hi;
                uint64_t pk = (uint64_t)pk2bf(ct[ht][4 * a] * inv, ct[ht][4 * a + 1] * inv) |
                              ((uint64_t)pk2bf(ct[ht][4 * a + 2] * inv, ct[ht][4 * a + 3] * inv) << 32);
                *(uint64_t*)&ctxb[base + hd] = pk;
            }
    } else {
        const float srow = ssum + __shfl_xor(ssum, 32);
        const int ti = (bh * 16 + qt) * 4 + seg;
        const int row = w * 32 + l31;
        u16* pp = &pctx[(size_t)ti * 8192 + row * 64];
#pragma unroll
        for (int ht = 0; ht < 2; ++ht)
#pragma unroll
            for (int a = 0; a < 4; ++a) {
                const int hd = ht * 32 + 8 * a + 4 * hi;
                uint64_t pk = (uint64_t)pk2bf(ct[ht][4 * a], ct[ht][4 * a + 1]) |
                              ((uint64_t)pk2bf(ct[ht][4 * a + 2], ct[ht][4 * a + 3]) << 32);
                *(uint64_t*)&pp[hd] = pk;
            }
        if (hi == 0) {
            pm[ti * 128 + row] = m2;
            ps[ti * 128 + row] = srow;
        }
    }
#undef STAGE32
}

// ---------------- split-K combine: merge <=4 segments per 128-row tile ----------------
__global__ __launch_bounds__(256) void k_attn_combine(const u16* __restrict__ pctx,
                                                      const float* __restrict__ pm,
                                                      const float* __restrict__ ps,
                                                      u16* __restrict__ ctxb) {
    const int bh = blockIdx.x, qt = blockIdx.y + 4;
    const int nseg = (2 * (qt + 1) + 7) >> 3;
    const int tb = (bh * 16 + qt) * 4;
    const int b = bh / 12, h = bh - b * 12;
#pragma unroll
    for (int it = 0; it < 2; ++it) {
        const int u = threadIdx.x + it * 256;
        const int row = u >> 2, h0 = (u & 3) * 16;
        float mv[4], sv[4];
#pragma unroll
        for (int s = 0; s < 4; ++s) {
            mv[s] = (s < nseg) ? pm[(tb + s) * 128 + row] : -1e30f;
            sv[s] = (s < nseg) ? ps[(tb + s) * 128 + row] : 0.0f;
        }
        const float mstar = fmaxf(fmaxf(mv[0], mv[1]), fmaxf(mv[2], mv[3]));
        float wv[4], S = 0.0f;
#pragma unroll
        for (int s = 0; s < 4; ++s) {
            wv[s] = __builtin_amdgcn_exp2f(mv[s] - mstar);
            S += wv[s] * sv[s];
        }
        float acc[16] = {};
#pragma unroll
        for (int s = 0; s < 4; ++s) {
            if (s < nseg) {
                const u16* pp = &pctx[(size_t)(tb + s) * 8192 + row * 64 + h0];
                const float wgt = wv[s];
#pragma unroll
                for (int e = 0; e < 2; ++e) {
                    s16x8 v = *(const s16x8*)(pp + e * 8);
#pragma unroll
                    for (int x = 0; x < 8; ++x)
                        acc[e * 8 + x] += wgt * bf2f((u16)v[x]);
                }
            }
        }
        const float inv = 1.0f / S;
        u16* op = &ctxb[(size_t)(b * 2048 + qt * 128 + row) * 768 + h * 64 + h0];
        s16x8 o0, o1;
#pragma unroll
        for (int x = 0; x < 8; ++x) {
            o0[x] = (short)f2bf(acc[x] * inv);
            o1[x] = (short)f2bf(acc[8 + x] * inv);
        }
        *(s16x8*)op = o0;
        *(s16x8*)(op + 8) = o1;
    }
}

// ---------------- launch ----------------
extern "C" void kernel_launch(void* const* d_in, const int* in_sizes, int n_in,
                              void* d_out, int out_size, void* d_ws, size_t ws_size,
                              hipStream_t stream) {
    (void)in_sizes; (void)n_in; (void)out_size; (void)ws_size;
    const float* x  = (const float*)d_in[0];
    const float* Wq = (const float*)d_in[1];
    const float* bq = (const float*)d_in[2];
    const float* Wk = (const float*)d_in[3];
    const float* bk = (const float*)d_in[4];
    const float* Wv = (const float*)d_in[5];
    const float* bv = (const float*)d_in[6];
    const float* Wo = (const float*)d_in[7];
    const float* bo = (const float*)d_in[8];
    char* ws = (char*)d_ws;
    u16* xb   = (u16*)(ws);               // 4096*768 bf16      = 6291456 B
    u16* wqt  = (u16*)(ws + 6291456);     // 768*768 bf16 (W^T) = 1179648 B
    u16* wkt  = (u16*)(ws + 7471104);
    u16* wvt  = (u16*)(ws + 8650752);
    u16* wot  = (u16*)(ws + 9830400);
    u16* qwv  = (u16*)(ws + 11010048);    // [24][2048][64] bf16 (Q pre-scaled by C2)
    u16* kwv  = (u16*)(ws + 17301504);
    u16* vtw  = (u16*)(ws + 23592960);    // V^T [24][64][2048] bf16
    u16* ctx  = (u16*)(ws + 29884416);    // [4096][768] bf16, ends 36175872
    u16* pctx = (u16*)(ws + 36175872);    // [24][16][4][128][64] bf16 = 25165824 B
    float* pm = (float*)(ws + 61341696);  // [24][16][4][128] f32 = 786432 B
    float* psu= (float*)(ws + 62128128);  // [24][16][4][128] f32 = 786432 B
    float* out = (float*)d_out;

    k_prep<<<3840, 256, 0, stream>>>(x, xb, Wq, Wk, Wv, Wo, wqt, wkt, wvt, wot);
    k_gemm_qkv<<<1152, 256, 0, stream>>>(xb, wqt, wkt, wvt, bq, bk, bv, qwv, kwv, vtw);
    k_attn<<<960, 256, 0, stream>>>(qwv, kwv, vtw, ctx, pctx, pm, psu);
    k_attn_combine<<<dim3(24, 12), 256, 0, stream>>>(pctx, pm, psu, ctx);
    k_gemm_out<<<768, 256, 0, stream>>>(ctx, wot, bo, out);
}